// Round 2
// baseline (67.464 us; speedup 1.0000x reference)
//
#include <hip/hip_runtime.h>

#define NT 256
#define SPLIT 4   // sub-blocks per row-group pair

__device__ __forceinline__ float pair_loss(float ti_t, float ti_p, float tj_t, float tj_p, float margin) {
    float td = ti_t - tj_t;
    float pd = ti_p - tj_p;
    float cs = copysignf(1.0f, td);            // v_bfi, single op; ties (td==0) negligible off-diagonal
    return fmaxf(fmaf(-cs, pd, margin), 0.0f); // fma with neg modifier + max
}

__global__ __launch_bounds__(NT)
void margin_kernel(const float* __restrict__ targets, int N, float* __restrict__ margin_out)
{
    __shared__ double red[2 * (NT / 64)];
    const int tid = threadIdx.x, lane = tid & 63, wave = tid >> 6;
    double s = 0.0, s2 = 0.0;
    const int n4 = N >> 2;
    const float4* t4 = (const float4*)targets;
    for (int i = tid; i < n4; i += NT) {
        float4 v = t4[i];
        s  += (double)v.x + (double)v.y + (double)v.z + (double)v.w;
        s2 += (double)v.x * v.x + (double)v.y * v.y + (double)v.z * v.z + (double)v.w * v.w;
    }
    for (int i = (n4 << 2) + tid; i < N; i += NT) { float t = targets[i]; s += t; s2 += (double)t * t; }
    #pragma unroll
    for (int off = 32; off; off >>= 1) { s += __shfl_down(s, off, 64); s2 += __shfl_down(s2, off, 64); }
    if (lane == 0) { red[wave] = s; red[NT / 64 + wave] = s2; }
    __syncthreads();
    if (tid == 0) {
        double S = 0.0, S2 = 0.0;
        for (int w = 0; w < NT / 64; ++w) { S += red[w]; S2 += red[NT / 64 + w]; }
        double mean = S / (double)N;
        double var = (S2 - (double)N * mean * mean) / (double)(N - 1);
        margin_out[0] = (float)(0.25 * sqrt(var > 0.0 ? var : 0.0));
    }
}

__global__ __launch_bounds__(NT, 8)
void pair_kernel(const float* __restrict__ preds, const float* __restrict__ targets,
                 const float* __restrict__ margin_p, float* __restrict__ out,
                 double* __restrict__ acc, unsigned int* __restrict__ cnt,
                 int N, double inv_pairs)
{
    const int tid  = threadIdx.x;
    const int lane = tid & 63;
    const int wave = tid >> 6;
    const float margin = margin_p[0];
    const int pairi = (int)(blockIdx.x >> 2);         // / SPLIT
    const int sub   = (int)(blockIdx.x & (SPLIT - 1));
    const int G = N >> 3;                              // groups of 8 rows
    const int P = G >> 1;                              // group pairs

    float av[8];
    #pragma unroll
    for (int k = 0; k < 8; ++k) av[k] = 0.0f;
    double extra = 0.0;

    if (pairi < P) {
        #pragma unroll
        for (int side = 0; side < 2; ++side) {
            const int gg = side ? (G - 1 - pairi) : pairi;
            const int i0 = gg << 3;
            float tg[8], pg[8];
            #pragma unroll
            for (int k = 0; k < 8; ++k) { tg[k] = targets[i0 + k]; pg[k] = preds[i0 + k]; }

            // intra-group 8x8 strict upper triangle (28 pairs), one wave, exact tie semantics
            if (sub == side && tid < 64) {
                int ii = tid >> 3, jj = tid & 7;
                if (ii < jj) {
                    float td = tg[ii] - tg[jj], pd = pg[ii] - pg[jj];
                    float cs = (td > 0.0f) ? 1.0f : ((td < 0.0f) ? -1.0f : 0.0f);
                    extra += (double)fmaxf(fmaf(-cs, pd, margin), 0.0f);
                }
            }

            const int lo = i0 + 8;
            const int len = N - lo;
            for (int idx = (sub << 8) + tid; idx < len; idx += NT * SPLIT) {
                const int j = lo + idx;
                const float t = targets[j];
                const float p = preds[j];
                #pragma unroll
                for (int k = 0; k < 8; ++k) {
                    av[k] += pair_loss(tg[k], pg[k], t, p, margin);
                }
            }
        }
    }

    // ---- leftovers (dead for N % 16 == 0): middle group when G odd, rows beyond 8G ----
    if (pairi == 0) {
        if (G & 1) {
            const int i0 = (G >> 1) << 3;
            for (int k = 0; k < 8; ++k) {
                const int i = i0 + k;
                for (int j = i + 1 + (sub << 8) + tid; j < N; j += NT * SPLIT) {
                    float td = targets[i] - targets[j], pd = preds[i] - preds[j];
                    float cs = (td > 0.0f) ? 1.0f : ((td < 0.0f) ? -1.0f : 0.0f);
                    extra += (double)fmaxf(fmaf(-cs, pd, margin), 0.0f);
                }
            }
        }
        for (int i = G << 3; i < N; ++i) {
            for (int j = i + 1 + (sub << 8) + tid; j < N; j += NT * SPLIT) {
                float td = targets[i] - targets[j], pd = preds[i] - preds[j];
                float cs = (td > 0.0f) ? 1.0f : ((td < 0.0f) ? -1.0f : 0.0f);
                extra += (double)fmaxf(fmaf(-cs, pd, margin), 0.0f);
            }
        }
    }

    // ---- reduce ----
    double tot = extra;
    #pragma unroll
    for (int k = 0; k < 8; ++k) tot += (double)av[k];
    #pragma unroll
    for (int off = 32; off; off >>= 1) tot += __shfl_down(tot, off, 64);
    __shared__ double red[NT / 64];
    if (lane == 0) red[wave] = tot;
    __syncthreads();
    if (tid == 0) {
        double bt = 0.0;
        for (int w = 0; w < NT / 64; ++w) bt += red[w];
        atomicAdd(acc, bt);
        __threadfence();
        unsigned prev = atomicAdd(cnt, 1u);
        if (prev == gridDim.x - 1) {
            double T = atomicAdd(acc, 0.0);   // device-scope atomic read of final value
            out[0] = (float)(T * inv_pairs);
        }
    }
}

extern "C" void kernel_launch(void* const* d_in, const int* in_sizes, int n_in,
                              void* d_out, int out_size, void* d_ws, size_t ws_size,
                              hipStream_t stream) {
    const float* preds   = (const float*)d_in[0];
    const float* targets = (const float*)d_in[1];
    float* out = (float*)d_out;
    int N = in_sizes[0];

    double*       acc  = (double*)d_ws;
    unsigned int* cnt  = (unsigned int*)((char*)d_ws + 8);
    float*        marg = (float*)((char*)d_ws + 16);
    hipMemsetAsync(d_ws, 0, 32, stream);

    margin_kernel<<<1, NT, 0, stream>>>(targets, N, marg);

    const int G = N >> 3;
    const int P = G >> 1;
    const int grid = (P > 0 ? P : 1) * SPLIT;
    const double inv_pairs = 2.0 / ((double)N * (double)(N - 1));
    pair_kernel<<<grid, NT, 0, stream>>>(preds, targets, marg, out, acc, cnt, N, inv_pairs);
}

// Round 3
// 18.115 us; speedup vs baseline: 3.7243x; 3.7243x over previous
//
#include <hip/hip_runtime.h>

#define NT 256
#define SPLIT 2   // sub-blocks per row-group pair (must be power of 2; code assumes 2)

__device__ __forceinline__ float pair_loss(float tt, float pp, float tj, float pj, float margin) {
    float td = tt - tj;
    float pd = pp - pj;
    float cs = copysignf(1.0f, td);            // ties land on +/-1; error per tie ~1e-7 of mean, negligible
    return fmaxf(fmaf(-cs, pd, margin), 0.0f);
}

__device__ __forceinline__ void do_j(float tj, float pj, const float* tg, const float* pg,
                                     float margin, float* av) {
    #pragma unroll
    for (int k = 0; k < 8; ++k) av[k] += pair_loss(tg[k], pg[k], tj, pj, margin);
}

__global__ __launch_bounds__(NT, 4)
void pair_kernel(const float* __restrict__ preds, const float* __restrict__ targets,
                 double* __restrict__ partials, int N)
{
    const int tid = threadIdx.x, lane = tid & 63, wave = tid >> 6;
    __shared__ double red[2 * (NT / 64)];
    __shared__ float smargin;

    // ---- per-block redundant margin = 0.25 * std(targets, ddof=1) ----
    double s = 0.0, s2 = 0.0;
    const int n4 = N >> 2;
    const float4* t4 = (const float4*)targets;
    for (int i = tid; i < n4; i += NT) {
        float4 v = t4[i];
        s  += (double)v.x + (double)v.y + (double)v.z + (double)v.w;
        s2 += (double)v.x * v.x + (double)v.y * v.y + (double)v.z * v.z + (double)v.w * v.w;
    }
    for (int i = (n4 << 2) + tid; i < N; i += NT) { float t = targets[i]; s += t; s2 += (double)t * t; }
    #pragma unroll
    for (int off = 32; off; off >>= 1) { s += __shfl_down(s, off, 64); s2 += __shfl_down(s2, off, 64); }
    if (lane == 0) { red[wave] = s; red[NT / 64 + wave] = s2; }
    __syncthreads();
    if (tid == 0) {
        double S = 0.0, S2 = 0.0;
        for (int w = 0; w < NT / 64; ++w) { S += red[w]; S2 += red[NT / 64 + w]; }
        double mean = S / (double)N;
        double var  = (S2 - (double)N * mean * mean) / (double)(N - 1);
        smargin = (float)(0.25 * sqrt(var > 0.0 ? var : 0.0));
    }
    __syncthreads();
    const float margin = smargin;

    // ---- all-pairs, 8-row register blocking, paired groups for uniform work ----
    const int G = N >> 3;                 // groups of 8 rows
    const int P = G >> 1;                 // group pairs (g, G-1-g)
    const int NB = (int)gridDim.x;        // multiple of SPLIT
    const int sub = (int)(blockIdx.x & (SPLIT - 1));
    const int pairblk = (int)(blockIdx.x >> 1);
    const int PSTRIDE = NB >> 1;

    float av[8];
    #pragma unroll
    for (int k = 0; k < 8; ++k) av[k] = 0.0f;
    double extra = 0.0;

    for (int p = pairblk; p < P; p += PSTRIDE) {
        #pragma unroll
        for (int side = 0; side < 2; ++side) {
            const int gg = side ? (G - 1 - p) : p;
            const int i0 = gg << 3;
            float tg[8], pg[8];
            #pragma unroll
            for (int k = 0; k < 8; ++k) { tg[k] = targets[i0 + k]; pg[k] = preds[i0 + k]; }

            // intra-group 8x8 strict upper triangle (28 pairs), exact tie semantics
            if (sub == side && tid < 64) {
                int ii = tid >> 3, jj = tid & 7;
                if (ii < jj) {
                    float td = tg[ii] - tg[jj], pd = pg[ii] - pg[jj];
                    float cs = (td > 0.0f) ? 1.0f : ((td < 0.0f) ? -1.0f : 0.0f);
                    extra += (double)fmaxf(fmaf(-cs, pd, margin), 0.0f);
                }
            }

            const int lo = i0 + 8;            // multiple of 8 -> float4 aligned
            const int len = N - lo;
            const int len4 = len >> 2;
            const float4* tj4 = (const float4*)(targets + lo);
            const float4* pj4 = (const float4*)(preds + lo);
            for (int idx = sub * NT + tid; idx < len4; idx += NT * SPLIT) {
                float4 tv = tj4[idx];
                float4 pv = pj4[idx];
                do_j(tv.x, pv.x, tg, pg, margin, av);
                do_j(tv.y, pv.y, tg, pg, margin, av);
                do_j(tv.z, pv.z, tg, pg, margin, av);
                do_j(tv.w, pv.w, tg, pg, margin, av);
            }
            // scalar remainder (dead when N % 8 == 0)
            for (int j = lo + (len4 << 2) + sub * NT + tid; j < N; j += NT * SPLIT) {
                do_j(targets[j], preds[j], tg, pg, margin, av);
            }
        }
    }

    // ---- leftovers for general N (dead when N % 16 == 0) ----
    if (pairblk == 0) {
        if (G & 1) {
            const int i0 = (G >> 1) << 3;
            for (int k = 0; k < 8 && i0 + k < N; ++k) {
                const int i = i0 + k;
                for (int j = i + 1 + sub * NT + tid; j < N; j += NT * SPLIT) {
                    float td = targets[i] - targets[j], pd = preds[i] - preds[j];
                    float cs = (td > 0.0f) ? 1.0f : ((td < 0.0f) ? -1.0f : 0.0f);
                    extra += (double)fmaxf(fmaf(-cs, pd, margin), 0.0f);
                }
            }
        }
        for (int i = G << 3; i < N; ++i) {
            for (int j = i + 1 + sub * NT + tid; j < N; j += NT * SPLIT) {
                float td = targets[i] - targets[j], pd = preds[i] - preds[j];
                float cs = (td > 0.0f) ? 1.0f : ((td < 0.0f) ? -1.0f : 0.0f);
                extra += (double)fmaxf(fmaf(-cs, pd, margin), 0.0f);
            }
        }
    }

    // ---- block reduce, plain store (no atomics, no fences) ----
    double tot = extra;
    #pragma unroll
    for (int k = 0; k < 8; ++k) tot += (double)av[k];
    #pragma unroll
    for (int off = 32; off; off >>= 1) tot += __shfl_down(tot, off, 64);
    __syncthreads();
    if (lane == 0) red[wave] = tot;
    __syncthreads();
    if (tid == 0) {
        double bt = 0.0;
        for (int w = 0; w < NT / 64; ++w) bt += red[w];
        partials[blockIdx.x] = bt;
    }
}

__global__ __launch_bounds__(NT)
void finalize_kernel(const double* __restrict__ partials, int nparts,
                     float* __restrict__ out, double inv_pairs)
{
    __shared__ double red[NT / 64];
    const int tid = threadIdx.x, lane = tid & 63, wave = tid >> 6;
    double s = 0.0;
    for (int i = tid; i < nparts; i += NT) s += partials[i];
    #pragma unroll
    for (int off = 32; off; off >>= 1) s += __shfl_down(s, off, 64);
    if (lane == 0) red[wave] = s;
    __syncthreads();
    if (tid == 0) {
        double t = 0.0;
        for (int w = 0; w < NT / 64; ++w) t += red[w];
        out[0] = (float)(t * inv_pairs);
    }
}

extern "C" void kernel_launch(void* const* d_in, const int* in_sizes, int n_in,
                              void* d_out, int out_size, void* d_ws, size_t ws_size,
                              hipStream_t stream) {
    const float* preds   = (const float*)d_in[0];
    const float* targets = (const float*)d_in[1];
    float* out = (float*)d_out;
    int N = in_sizes[0];

    double* partials = (double*)d_ws;
    const int G = N >> 3;
    const int P = G >> 1;

    int NB = (P > 0 ? P : 1) * SPLIT;
    if (NB > 1024) NB = 1024;
    int maxParts = (int)(ws_size / sizeof(double));
    if (NB > maxParts) NB = (maxParts / SPLIT) * SPLIT;
    if (NB < SPLIT) NB = SPLIT;

    const double inv_pairs = 2.0 / ((double)N * (double)(N - 1));
    pair_kernel<<<NB, NT, 0, stream>>>(preds, targets, partials, N);
    finalize_kernel<<<1, NT, 0, stream>>>(partials, NB, out, inv_pairs);
}